// Round 6
// baseline (766.244 us; speedup 1.0000x reference)
//
#include <hip/hip_runtime.h>

#define NPB 6            // nodes per block in mega_kernel
#define BN_SHIFT 8       // 256 nodes per bucket
#define NBMAX 512        // max buckets (N up to 131072)
#define CHUNK 4096       // edges per bin_kernel block

__device__ __forceinline__ float leaky(float x) { return fmaxf(x, 0.1f * x); }

// ---------------- K0: coarse bucket histogram (LDS-aggregated) ----------------
__global__ __launch_bounds__(256) void bhist_kernel(const int* __restrict__ src,
                                                    int* __restrict__ bhist, int E, int NB)
{
    __shared__ int h[NBMAX];
    for (int i = threadIdx.x; i < NB; i += 256) h[i] = 0;
    __syncthreads();
    int stride = gridDim.x * 256;
    for (int i = blockIdx.x * 256 + threadIdx.x; i < E; i += stride)
        atomicAdd(&h[src[i] >> BN_SHIFT], 1);
    __syncthreads();
    for (int i = threadIdx.x; i < NB; i += 256) if (h[i]) atomicAdd(&bhist[i], h[i]);
}

// ---------------- K1: scan bucket sizes -> bases & cursors ----------------
__global__ __launch_bounds__(64) void bscan_kernel(const int* __restrict__ bhist,
                                                   int* __restrict__ bbase,
                                                   int* __restrict__ bcur, int E, int NB)
{
    int lane = threadIdx.x;
    int carry = 0;
    for (int base = 0; base < NB; base += 64) {
        int i = base + lane;
        int v = (i < NB) ? bhist[i] : 0;
        int inc = v;
#pragma unroll
        for (int d = 1; d < 64; d <<= 1) { int m = __shfl_up(inc, d); if (lane >= d) inc += m; }
        if (i < NB) { bbase[i] = inc - v + carry; bcur[i] = inc - v + carry; }
        carry += __shfl(inc, 63);
    }
    if (lane == 0) bbase[NB] = E;
}

// ---------------- K2: bin pass — bucket-group edges, carry payload ----------------
// record = 3 float4: [ea0..ea9, tgt_as_float_bits, pad]
__global__ __launch_bounds__(1024) void bin_kernel(const int* __restrict__ edge_index,
                                                   const float* __restrict__ edge_attr,
                                                   int* __restrict__ bcur,
                                                   int* __restrict__ bin_key,
                                                   float4* __restrict__ bin_rec, int E, int NB)
{
    __shared__ int hist[NBMAX], baseg[NBMAX], cur[NBMAX];
    int tid = threadIdx.x;
    int cbase = blockIdx.x * CHUNK;
    int n = min(CHUNK, E - cbase);

    for (int i = tid; i < NB; i += 1024) { hist[i] = 0; cur[i] = 0; }
    __syncthreads();

    int msrc[4], mtgt[4];
#pragma unroll
    for (int q = 0; q < 4; q++) {
        int i = tid + q * 1024;
        if (i < n) {
            msrc[q] = edge_index[cbase + i];
            mtgt[q] = edge_index[E + cbase + i];
            atomicAdd(&hist[msrc[q] >> BN_SHIFT], 1);
        }
    }
    __syncthreads();

    for (int i = tid; i < NB; i += 1024) {
        int c = hist[i];
        baseg[i] = c ? atomicAdd(&bcur[i], c) : 0;
    }
    __syncthreads();

#pragma unroll
    for (int q = 0; q < 4; q++) {
        int i = tid + q * 1024;
        if (i < n) {
            int b = msrc[q] >> BN_SHIFT;
            int r = atomicAdd(&cur[b], 1);
            int gp = baseg[b] + r;
            const float2* ea = (const float2*)(edge_attr + (size_t)(cbase + i) * 10);
            float2 a0 = ea[0], a1 = ea[1], a2 = ea[2], a3 = ea[3], a4 = ea[4];
            float4* dst = bin_rec + (size_t)gp * 3;
            dst[0] = make_float4(a0.x, a0.y, a1.x, a1.y);
            dst[1] = make_float4(a2.x, a2.y, a3.x, a3.y);
            dst[2] = make_float4(a4.x, a4.y, __int_as_float(mtgt[q]), 0.f);
            bin_key[gp] = msrc[q];
        }
    }
}

// ---------------- K3: within-bucket exact sort -> node offsets + index perm ----------------
__global__ __launch_bounds__(512) void bsort_kernel(const int* __restrict__ bin_key,
                                                    const int* __restrict__ bbase,
                                                    int* __restrict__ offsets,
                                                    int* __restrict__ perm_idx, int N)
{
    __shared__ int hist[256], cur[256];
    int tid = threadIdx.x;
    int b = blockIdx.x;
    int node0 = b << BN_SHIFT;
    int lo = bbase[b], hi = bbase[b + 1];

    if (tid < 256) hist[tid] = 0;
    __syncthreads();
    for (int i = lo + tid; i < hi; i += 512) atomicAdd(&hist[bin_key[i] - node0], 1);
    __syncthreads();
    if (tid < 64) {
        int carry = 0;
        for (int base = 0; base < 256; base += 64) {
            int i = base + tid;
            int v = hist[i];
            int inc = v;
#pragma unroll
            for (int d = 1; d < 64; d <<= 1) { int m = __shfl_up(inc, d); if (tid >= d) inc += m; }
            cur[i] = inc - v + carry;
            carry += __shfl(inc, 63);
        }
    }
    __syncthreads();
    if (tid < 256) {
        int node = node0 + tid;
        if (node < N) offsets[node] = lo + cur[tid];
    }
    __syncthreads();
    for (int i = lo + tid; i < hi; i += 512) {
        int s = bin_key[i];
        int p = lo + atomicAdd(&cur[s - node0], 1);
        perm_idx[p] = i;
    }
}

// ---------------- K4: fused record-read + edge MLP + moments + node MLP ----------------
__global__ __launch_bounds__(256) void mega_kernel(
    const float* __restrict__ x_t, const float4* __restrict__ bin_rec,
    const int* __restrict__ perm_idx, const int* __restrict__ offsets,
    const float* __restrict__ x_s, const float* __restrict__ u,
    const int* __restrict__ batch_s,
    const float* __restrict__ w1a, const float* __restrict__ b1a,
    const float* __restrict__ w2a, const float* __restrict__ b2a,
    const float* __restrict__ w1b, const float* __restrict__ b1b,
    const float* __restrict__ w2b, const float* __restrict__ b2b,
    float* __restrict__ out, int N, int E)
{
    __shared__ float ys[256 * 17];
    __shared__ float sw1[240], sw2[240];
    __shared__ float sb1[16], sb2[16];
    __shared__ float tw1[810], tw2[100], tb1[16], tb2[16];
    __shared__ float accs[NPB * 64];
    __shared__ float harr[NPB * 81];
    __shared__ float o1s[NPB * 10];
    __shared__ int   nstart[NPB + 1];

    int tid = threadIdx.x;

    for (int i = tid; i < 240; i += 256) {
        int r = i >> 4, c = i & 15;
        sw1[i] = (c < 15) ? w1a[r * 15 + c] : 0.f;
        sw2[i] = (c < 15) ? w2a[r * 15 + c] : 0.f;
    }
    for (int i = tid; i < 810; i += 256) tw1[i] = w1b[i];
    for (int i = tid; i < 100; i += 256) tw2[i] = w2b[i];
    if (tid < 15) { sb1[tid] = b1a[tid]; sb2[tid] = b2a[tid]; }
    if (tid < 10) { tb1[tid] = b1b[tid]; tb2[tid] = b2b[tid]; }
    for (int i = tid; i < NPB * 64; i += 256) accs[i] = 0.f;

    int n0 = blockIdx.x * NPB;
    int nn = min(NPB, N - n0);
    if (tid <= nn) nstart[tid] = (n0 + tid < N) ? offsets[n0 + tid] : E;
    __syncthreads();

    int e_lo = nstart[0], e_hi = nstart[nn];
    int nchunks = (e_hi - e_lo + 255) >> 8;

    int f = tid & 15, sub = tid >> 4, lane = tid & 63;

    for (int c = 0; c < nchunks; ++c) {
        int base = e_lo + (c << 8);
        int ce = min(256, e_hi - base);

        // ---- phase A: record gather (L2-window) + edge MLP into LDS ----
        if (tid < ce) {
            int idx = perm_idx[base + tid];
            const float4* rp = bin_rec + (size_t)idx * 3;
            float4 r0 = rp[0], r1 = rp[1], r2 = rp[2];
            int tgt = __float_as_int(r2.z);

            float in0[15];
            const float* xt = x_t + (size_t)tgt * 5;
#pragma unroll
            for (int q = 0; q < 5; q++) in0[q] = xt[q];
            in0[5] = r0.x;  in0[6] = r0.y;  in0[7] = r0.z;  in0[8] = r0.w;
            in0[9] = r1.x;  in0[10] = r1.y; in0[11] = r1.z; in0[12] = r1.w;
            in0[13] = r2.x; in0[14] = r2.y;

            float h[15];
#pragma unroll
            for (int j = 0; j < 15; j++) h[j] = sb1[j];
#pragma unroll
            for (int i = 0; i < 15; i++)
#pragma unroll
                for (int j = 0; j < 15; j++) h[j] = fmaf(in0[i], sw1[i * 16 + j], h[j]);
#pragma unroll
            for (int j = 0; j < 15; j++) h[j] = leaky(h[j]);

            float y[15];
#pragma unroll
            for (int j = 0; j < 15; j++) y[j] = sb2[j];
#pragma unroll
            for (int i = 0; i < 15; i++)
#pragma unroll
                for (int j = 0; j < 15; j++) y[j] = fmaf(h[i], sw2[i * 16 + j], y[j]);
#pragma unroll
            for (int j = 0; j < 15; j++) ys[tid * 17 + j] = y[j];
        }
        __syncthreads();

        // ---- phase B: (feature, sub) threads accumulate moments from LDS ----
        for (int n = 0; n < nn; ++n) {
            int lo = max(nstart[n] - base, 0);
            int hi = min(nstart[n + 1] - base, ce);
            if (hi > lo) {
                float s1 = 0.f, s2 = 0.f, s3 = 0.f, s4 = 0.f;
                for (int k = lo + sub; k < hi; k += 16) {
                    float v = ys[k * 17 + f];
                    float v2 = v * v;
                    s1 += v; s2 += v2; s3 += v2 * v; s4 += v2 * v2;
                }
                s1 += __shfl_xor(s1, 16); s1 += __shfl_xor(s1, 32);
                s2 += __shfl_xor(s2, 16); s2 += __shfl_xor(s2, 32);
                s3 += __shfl_xor(s3, 16); s3 += __shfl_xor(s3, 32);
                s4 += __shfl_xor(s4, 16); s4 += __shfl_xor(s4, 32);
                if (lane < 16 && f < 15) {
                    atomicAdd(&accs[n * 64 + 1 + f],  s1);
                    atomicAdd(&accs[n * 64 + 16 + f], s2);
                    atomicAdd(&accs[n * 64 + 31 + f], s3);
                    atomicAdd(&accs[n * 64 + 46 + f], s4);
                }
            }
        }
        __syncthreads();
    }

    if (tid < nn * 16 && f < 15) {
        int n = tid >> 4;
        float cf  = (float)(nstart[n + 1] - nstart[n]);
        float inv = 1.0f / fmaxf(cf, 1.0f);
        float m1 = accs[n * 64 + 1 + f]  * inv;
        float m2 = accs[n * 64 + 16 + f] * inv;
        float m3 = accs[n * 64 + 31 + f] * inv;
        float m4 = accs[n * 64 + 46 + f] * inv;
        float var = fmaxf(m2 - m1 * m1, 0.0f);
        float sd  = sqrtf(var + 1e-6f);
        float m1sq = m1 * m1;
        float c3 = m3 - 3.0f * m1 * m2 + 2.0f * m1sq * m1;
        float c4 = m4 - 4.0f * m1 * m3 + 6.0f * m1sq * m2 - 3.0f * m1sq * m1sq;
        float is = 1.0f / sd;
        float is2 = is * is;
        harr[n * 81 + 11 + f] = m1;
        harr[n * 81 + 26 + f] = sd;
        harr[n * 81 + 41 + f] = c3 * is2 * is;
        harr[n * 81 + 56 + f] = c4 * is2 * is2;
    }
    if (tid < nn * 10) {
        int n = tid / 10, q = tid % 10;
        harr[n * 81 + q]      = x_s[(size_t)(n0 + n) * 10 + q];
        harr[n * 81 + 71 + q] = u[(size_t)batch_s[n0 + n] * 10 + q];
    }
    if (tid < nn) harr[tid * 81 + 10] = (float)(nstart[tid + 1] - nstart[tid]);
    __syncthreads();

    if (tid < nn * 10) {
        int n = tid / 10, k = tid % 10;
        float a = tb1[k];
#pragma unroll
        for (int j = 0; j < 81; j++) a = fmaf(harr[n * 81 + j], tw1[j * 10 + k], a);
        o1s[n * 10 + k] = leaky(a);
    }
    __syncthreads();
    if (tid < nn * 10) {
        int n = tid / 10, k = tid % 10;
        float a = tb2[k];
#pragma unroll
        for (int m = 0; m < 10; m++) a = fmaf(o1s[n * 10 + m], tw2[m * 10 + k], a);
        out[(size_t)(n0 + n) * 10 + k] = a;
    }
}

extern "C" void kernel_launch(void* const* d_in, const int* in_sizes, int n_in,
                              void* d_out, int out_size, void* d_ws, size_t ws_size,
                              hipStream_t stream)
{
    const float* x_s       = (const float*)d_in[0];
    const float* x_t       = (const float*)d_in[1];
    const float* edge_attr = (const float*)d_in[2];
    const float* u         = (const float*)d_in[3];
    const int*   edge_index= (const int*)d_in[4];
    const int*   batch_s   = (const int*)d_in[5];
    const float* w1a = (const float*)d_in[6];
    const float* b1a = (const float*)d_in[7];
    const float* w2a = (const float*)d_in[8];
    const float* b2a = (const float*)d_in[9];
    const float* w1b = (const float*)d_in[10];
    const float* b1b = (const float*)d_in[11];
    const float* w2b = (const float*)d_in[12];
    const float* b2b = (const float*)d_in[13];

    int N = in_sizes[0] / 10;   // N_S
    int E = in_sizes[2] / 10;   // edge_attr [E,10]
    int NB = (N + (1 << BN_SHIFT) - 1) >> BN_SHIFT;

    // workspace layout (256-B aligned regions); total ~226 MB
    char* p = (char*)d_ws;
    auto take = [&](size_t bytes) { char* r = p; p += (bytes + 255) & ~(size_t)255; return r; };
    int*    bhist    = (int*)take((size_t)NBMAX * 4);
    int*    bbase    = (int*)take((size_t)(NBMAX + 1) * 4);
    int*    bcur     = (int*)take((size_t)NBMAX * 4);
    int*    offsets  = (int*)take((size_t)N * 4);
    int*    bin_key  = (int*)take((size_t)E * 4);
    int*    perm_idx = (int*)take((size_t)E * 4);
    float4* bin_rec  = (float4*)take((size_t)E * 48);

    hipMemsetAsync(bhist, 0, (size_t)NB * sizeof(int), stream);

    bhist_kernel<<<512, 256, 0, stream>>>(edge_index, bhist, E, NB);
    bscan_kernel<<<1, 64, 0, stream>>>(bhist, bbase, bcur, E, NB);
    bin_kernel<<<(E + CHUNK - 1) / CHUNK, 1024, 0, stream>>>(
        edge_index, edge_attr, bcur, bin_key, bin_rec, E, NB);
    bsort_kernel<<<NB, 512, 0, stream>>>(bin_key, bbase, offsets, perm_idx, N);
    mega_kernel<<<(N + NPB - 1) / NPB, 256, 0, stream>>>(
        x_t, bin_rec, perm_idx, offsets,
        x_s, u, batch_s,
        w1a, b1a, w2a, b2a, w1b, b1b, w2b, b2b,
        (float*)d_out, N, E);
}